// Round 1
// 768.844 us; speedup vs baseline: 1.0768x; 1.0768x over previous
//
#include <hip/hip_runtime.h>
#include <stdint.h>

typedef _Float16 h2 __attribute__((ext_vector_type(2)));
typedef _Float16 h8 __attribute__((ext_vector_type(8)));
typedef float f32x4 __attribute__((ext_vector_type(4)));

__device__ __forceinline__ uint32_t pk_cvt(float a, float b) {
  return __builtin_bit_cast(uint32_t, __builtin_amdgcn_cvt_pkrtz(a, b));
}

__device__ __forceinline__ uint32_t dq(uint32_t t, h2 z2, h2 s2) {
  // t = two f16 (1024+n_lo, 1024+n_hi); exact integer subtract, one rounded mul
  h2 v = __builtin_bit_cast(h2, t);
  h2 w = (v - z2) * s2;
  return __builtin_bit_cast(uint32_t, w);
}

__device__ __forceinline__ uint32_t dq_lin(uint32_t u, h2 z2, h2 s2) {
  // nibbles at bits 0-3 and 4-7 of u -> linear pair (k, k+1)
  uint32_t t = (u & 0xFu) | ((u & 0xF0u) << 12) | 0x64006400u;
  return dq(t, z2, s2);
}

typedef __attribute__((address_space(1))) const uint32_t* gas_ptr;
typedef __attribute__((address_space(3))) uint32_t* las_ptr;
__device__ __forceinline__ void gll16(const _Float16* g, _Float16* l) {
  // lane i lands at l + i*16B (wave-uniform base); 16B per lane
  __builtin_amdgcn_global_load_lds((gas_ptr)g, (las_ptr)l, 16, 0, 0);
}

#define WAITVM(n) asm volatile("s_waitcnt vmcnt(" #n ")" ::: "memory")

// ---------------- phase 1: x fp32 -> f16 (linear k order) ----------------
__global__ __launch_bounds__(256) void cvt_x_kernel(const float* __restrict__ x,
                                                    _Float16* __restrict__ xh,
                                                    size_t n) {
  size_t i = ((size_t)blockIdx.x * 256 + threadIdx.x) * 8;
  if (i >= n) return;
  float4 a = *(const float4*)(x + i);
  float4 b = *(const float4*)(x + i + 4);
  uint4 v = make_uint4(pk_cvt(a.x, a.y), pk_cvt(a.z, a.w),
                       pk_cvt(b.x, b.y), pk_cvt(b.z, b.w));
  *(uint4*)(xh + i) = v;
}

// -------- phase 2: dequant qweight -> W^T f16 [N][K], linear k ----------
__global__ __launch_bounds__(256) void dequant_w_kernel(
    const uint32_t* __restrict__ qweight, const uint32_t* __restrict__ qzeros,
    const float* __restrict__ scales, _Float16* __restrict__ wt, int N, int K) {
  __shared__ uint32_t qw[8][64];
  const int t = threadIdx.x;
  const int n0 = blockIdx.x * 64;
  const int kp0 = blockIdx.y * 8;  // 8 packed words = 64 k, inside one group

  {  // coalesced load of the [8 kp][64 n] tile
    int r = t >> 6, c = t & 63;
    qw[r][c]     = qweight[(size_t)(kp0 + r) * N + n0 + c];
    qw[r + 4][c] = qweight[(size_t)(kp0 + r + 4) * N + n0 + c];
  }
  __syncthreads();

  const int nl = t >> 2;           // output row (column of W) 0..63
  const int kpl = (t & 3) * 2;     // this thread's 2 packed words
  const int n = n0 + nl;
  const int g = kp0 >> 4;          // group = k/128 = kp/16
  uint32_t qz = qzeros[(size_t)g * (N >> 3) + (n >> 3)];
  int zp = (qz >> ((n & 7) * 4)) & 15;
  float sc = scales[(size_t)g * N + n];
  _Float16 hz = (_Float16)(float)(1024 + zp + 1);
  _Float16 hs = (_Float16)sc;
  h2 z2 = {hz, hz};
  h2 s2 = {hs, hs};

#pragma unroll
  for (int w = 0; w < 2; ++w) {
    uint32_t word = qw[kpl + w][nl];
    uint4 v = make_uint4(dq_lin(word, z2, s2), dq_lin(word >> 8, z2, s2),
                         dq_lin(word >> 16, z2, s2), dq_lin(word >> 24, z2, s2));
    *(uint4*)(wt + (size_t)n * K + (size_t)(kp0 + kpl + w) * 8) = v;
  }
}

// ------------- phase 3a: 256x256 tile, 4-deep ring, counted vmcnt -------
// A [M][K] f16, B [N][K] f16 (W^T). BK=32. 8 waves (2M x 4N), per-wave
// output 128x64. LDS: 4 bufs x (A 16KB + B 16KB) = 128 KiB.
// Per K-tile: 1x s_waitcnt vmcnt(8) (tiles t+1,t+2 stay in flight; never
// drains to 0) + 1x s_barrier; 4 quadrant phases interleaving ds_read /
// global_load_lds (tile t+3) / MFMA. LDS XOR-swizzle slot^=(row&3) applied
// via pre-swizzled per-lane GLOBAL source (gll writes linearly) + swizzled
// ds_read address (both-sides-or-neither, rule 21).
__global__ __launch_bounds__(512, 2) void gemm_f16_256(
    const _Float16* __restrict__ A, const _Float16* __restrict__ B,
    const float* __restrict__ bias, float* __restrict__ out,
    int M, int N, int K) {
  __shared__ _Float16 As[4][256 * 32];
  __shared__ _Float16 Bs[4][256 * 32];

  // bijective XCD-aware block swizzle (m204 form): consecutive same-XCD
  // blocks share the A row-panel (2 MB, L2-resident).
  const int gx = gridDim.x, gy = gridDim.y;
  const int nwg = gx * gy;
  const int lin = blockIdx.y * gx + blockIdx.x;
  const int xcd = lin & 7, idx = lin >> 3;
  const int q8 = nwg >> 3, r8 = nwg & 7;
  const int wg = (xcd < r8 ? xcd * (q8 + 1) : r8 * (q8 + 1) + (xcd - r8) * q8) + idx;
  const int bn0 = (wg % gx) * 256;
  const int bm0 = (wg / gx) * 256;

  const int tid = threadIdx.x;
  const int lane = tid & 63;
  const int wave = tid >> 6;     // 0..7
  const int wm = wave >> 2;      // 0..1 -> 128 rows
  const int wn = wave & 3;       // 0..3 -> 64 cols

  f32x4 acc[8][4];
#pragma unroll
  for (int i = 0; i < 8; ++i)
#pragma unroll
    for (int j = 0; j < 4; ++j) acc[i][j] = (f32x4)0.f;

  // ---- staging geometry: wave w stages rows [32w,32w+32) of A and B ----
  // chunk c (16 rows): lane i -> lds row 32w+16c+(i>>2), slot i&3.
  // source k-slot pre-swizzled: (i&3) ^ ((i>>2)&3).
  const int srow = lane >> 2;                     // 0..15
  const int sslot = (lane & 3) ^ (srow & 3);      // swizzled source slot
  const _Float16* pSa0 = A + (size_t)(bm0 + 32 * wave + srow) * K + sslot * 8;
  const _Float16* pSa1 = pSa0 + (size_t)16 * K;
  const _Float16* pSb0 = B + (size_t)(bn0 + 32 * wave + srow) * K + sslot * 8;
  const _Float16* pSb1 = pSb0 + (size_t)16 * K;
  const int dst_off = wave * 1024;                // halves: (32*wave)*32

  // ---- fragment read offsets (swizzled slot = (lane>>4) ^ (lane&3)) ----
  const int fslot = ((lane >> 4) ^ (lane & 3)) * 8;
  const int aoff = (wm * 128 + (lane & 15)) * 32 + fslot;
  const int boff = (wn * 64 + (lane & 15)) * 32 + fslot;

  const int nt = K >> 5;  // K-tiles of 32

  // ---- prologue: stage tiles 0,1,2 (4 gll per wave per tile) ----
#pragma unroll
  for (int u = 0; u < 3; ++u) {
    if (u < nt) {
      const size_t ko = (size_t)u * 32;
      _Float16* da = As[u & 3] + dst_off;
      _Float16* db = Bs[u & 3] + dst_off;
      gll16(pSa0 + ko, da);
      gll16(pSa1 + ko, da + 512);
      gll16(pSb0 + ko, db);
      gll16(pSb1 + ko, db + 512);
    }
  }

  for (int t = 0; t < nt; ++t) {
    // counted wait: tiles t+1, t+2 (8 gll per wave) remain in flight
    if (t + 2 < nt)      WAITVM(8);
    else if (t + 1 < nt) WAITVM(4);
    else                 WAITVM(0);
    __builtin_amdgcn_s_barrier();
    asm volatile("" ::: "memory");

    const int buf = t & 3;
    const _Float16* Ab = As[buf] + aoff;
    const _Float16* Bb = Bs[buf] + boff;

    h8 bfr[4];
#pragma unroll
    for (int j = 0; j < 4; ++j) bfr[j] = *(const h8*)(Bb + j * 512);

    const int ts = t + 3;
    const bool do_stage = ts < nt;
    const size_t ko = (size_t)ts * 32;
    _Float16* da = As[ts & 3] + dst_off;
    _Float16* db = Bs[ts & 3] + dst_off;
    if (do_stage) gll16(pSa0 + ko, da);

#pragma unroll
    for (int q = 0; q < 4; ++q) {
      h8 a0 = *(const h8*)(Ab + (2 * q) * 512);
      h8 a1 = *(const h8*)(Ab + (2 * q + 1) * 512);
      if (q == 1 && do_stage) gll16(pSa1 + ko, da + 512);
      if (q == 2 && do_stage) gll16(pSb0 + ko, db);
      if (q == 3 && do_stage) gll16(pSb1 + ko, db + 512);
      __builtin_amdgcn_s_setprio(1);
#pragma unroll
      for (int j = 0; j < 4; ++j) {
        acc[2 * q][j] = __builtin_amdgcn_mfma_f32_16x16x32_f16(
            a0, bfr[j], acc[2 * q][j], 0, 0, 0);
        acc[2 * q + 1][j] = __builtin_amdgcn_mfma_f32_16x16x32_f16(
            a1, bfr[j], acc[2 * q + 1][j], 0, 0, 0);
      }
      __builtin_amdgcn_s_setprio(0);
    }
  }

  // epilogue: D[row=(lane>>4)*4+rr][col=lane&15] per 16x16 tile
  const int r0 = bm0 + wm * 128 + ((lane >> 4) << 2);
  const int c0 = bn0 + wn * 64 + (lane & 15);
#pragma unroll
  for (int j = 0; j < 4; ++j) {
    const int c = c0 + j * 16;
    const float bv = bias[c];
#pragma unroll
    for (int i = 0; i < 8; ++i) {
#pragma unroll
      for (int rr = 0; rr < 4; ++rr)
        out[(size_t)(r0 + i * 16 + rr) * N + c] = acc[i][j][rr] + bv;
    }
  }
}

// ------------- phase 3b fallback: f16 GEMM, m97 structure ---------------
__global__ __launch_bounds__(256) void gemm_f16_kernel(
    const _Float16* __restrict__ A,   // [M][K] f16
    const _Float16* __restrict__ B,   // [N][K] f16 (W^T)
    const float* __restrict__ bias, float* __restrict__ out,
    int M, int N, int K) {
  __shared__ _Float16 As[128 * 32];   // unpadded: required by global_load_lds
  __shared__ _Float16 Bs[128 * 32];

  const int tid = threadIdx.x;
  const int lane = tid & 63;
  const int wave = tid >> 6;
  const int wm = wave & 1;
  const int wn = wave >> 1;
  const int bn0 = blockIdx.x * 128;
  const int bm0 = blockIdx.y * 128;

  f32x4 acc[4][4];
#pragma unroll
  for (int i = 0; i < 4; ++i)
#pragma unroll
    for (int j = 0; j < 4; ++j) acc[i][j] = (f32x4)0.f;

  const int srow = wave * 16 + (lane >> 2);
  const int skoff = (lane & 3) * 8;
  const _Float16* Ag0 = A + (size_t)(bm0 + srow) * K + skoff;
  const _Float16* Ag1 = A + (size_t)(bm0 + 64 + srow) * K + skoff;
  const _Float16* Bg0 = B + (size_t)(bn0 + srow) * K + skoff;
  const _Float16* Bg1 = B + (size_t)(bn0 + 64 + srow) * K + skoff;
  _Float16* Al0 = As + (wave * 16) * 32;
  _Float16* Al1 = As + (64 + wave * 16) * 32;
  _Float16* Bl0 = Bs + (wave * 16) * 32;
  _Float16* Bl1 = Bs + (64 + wave * 16) * 32;

  const _Float16* Af = As + (wm * 64 + (lane & 15)) * 32 + (lane >> 4) * 8;
  const _Float16* Bf = Bs + (wn * 64 + (lane & 15)) * 32 + (lane >> 4) * 8;

  for (int k0 = 0; k0 < K; k0 += 32) {
    gll16(Ag0 + k0, Al0);
    gll16(Ag1 + k0, Al1);
    gll16(Bg0 + k0, Bl0);
    gll16(Bg1 + k0, Bl1);
    __syncthreads();

    h8 af[4], bf[4];
#pragma unroll
    for (int i = 0; i < 4; ++i) {
      af[i] = *(const h8*)(Af + i * 16 * 32);
      bf[i] = *(const h8*)(Bf + i * 16 * 32);
    }
#pragma unroll
    for (int i = 0; i < 4; ++i)
#pragma unroll
      for (int j = 0; j < 4; ++j)
        acc[i][j] = __builtin_amdgcn_mfma_f32_16x16x32_f16(af[i], bf[j],
                                                           acc[i][j], 0, 0, 0);
    __syncthreads();
  }

  const int r0 = bm0 + wm * 64 + (lane >> 4) * 4;
  const int c0 = bn0 + wn * 64 + (lane & 15);
#pragma unroll
  for (int j = 0; j < 4; ++j) {
    const int c = c0 + j * 16;
    const float bv = bias[c];
#pragma unroll
    for (int i = 0; i < 4; ++i) {
#pragma unroll
      for (int rr = 0; rr < 4; ++rr) {
        out[(size_t)(r0 + i * 16 + rr) * N + c] = acc[i][j][rr] + bv;
      }
    }
  }
}

// ------------------- fallback: round-2 fused kernel ---------------------
#define LDK 40
__global__ __launch_bounds__(256) void gptq_gemm_fused(
    const float* __restrict__ x, const uint32_t* __restrict__ qweight,
    const uint32_t* __restrict__ qzeros, const float* __restrict__ scales,
    const float* __restrict__ bias, float* __restrict__ out,
    int M, int N, int K) {
  __shared__ _Float16 As[128 * LDK];
  __shared__ _Float16 Bs[128 * LDK];
  const int tid = threadIdx.x, lane = tid & 63, wave = tid >> 6;
  const int wm = wave & 1, wn = wave >> 1;
  const int bn0 = blockIdx.x * 128, bm0 = blockIdx.y * 128;
  const int sr = tid >> 1, sg0 = (tid & 1) * 2;
  const float* xrow = x + (size_t)(bm0 + sr) * K + sg0 * 8;
  const int colb = bn0 + sr;
  const int groups = K >> 7, NP = N >> 3;
  f32x4 acc[4][4];
#pragma unroll
  for (int i = 0; i < 4; ++i)
#pragma unroll
    for (int j = 0; j < 4; ++j) acc[i][j] = (f32x4)0.f;
  const _Float16* Ab = As + (wm * 64 + (lane & 15)) * LDK + (lane >> 4) * 8;
  const _Float16* Bb = Bs + (wn * 64 + (lane & 15)) * LDK + (lane >> 4) * 8;
  for (int g = 0; g < groups; ++g) {
    uint32_t qz = qzeros[(size_t)g * NP + (colb >> 3)];
    int zp = (qz >> ((colb & 7) * 4)) & 15;
    float sc = scales[(size_t)g * N + colb];
    _Float16 hz = (_Float16)(float)(1024 + zp + 1);
    _Float16 hs = (_Float16)sc;
    h2 z2 = {hz, hz}, s2 = {hs, hs};
#pragma unroll
    for (int kt = 0; kt < 4; ++kt) {
      const int k0 = g * 128 + kt * 32;
      const float* xr = xrow + k0;
      float4 fa0 = *(const float4*)(xr);
      float4 fa1 = *(const float4*)(xr + 4);
      float4 fa2 = *(const float4*)(xr + 8);
      float4 fa3 = *(const float4*)(xr + 12);
      const size_t kp = (size_t)(k0 >> 3) + sg0;
      uint32_t q0 = qweight[kp * N + colb];
      uint32_t q1 = qweight[(kp + 1) * N + colb];
      __syncthreads();
      uint4 av0 = make_uint4(pk_cvt(fa0.x, fa1.x), pk_cvt(fa0.y, fa1.y),
                             pk_cvt(fa0.z, fa1.z), pk_cvt(fa0.w, fa1.w));
      uint4 av1 = make_uint4(pk_cvt(fa2.x, fa3.x), pk_cvt(fa2.y, fa3.y),
                             pk_cvt(fa2.z, fa3.z), pk_cvt(fa2.w, fa3.w));
      *(uint4*)(As + sr * LDK + sg0 * 8) = av0;
      *(uint4*)(As + sr * LDK + sg0 * 8 + 8) = av1;
      uint4 bv0 = make_uint4(dq((q0 & 0x000F000Fu) | 0x64006400u, z2, s2),
                             dq(((q0 >> 4) & 0x000F000Fu) | 0x64006400u, z2, s2),
                             dq(((q0 >> 8) & 0x000F000Fu) | 0x64006400u, z2, s2),
                             dq(((q0 >> 12) & 0x000F000Fu) | 0x64006400u, z2, s2));
      uint4 bv1 = make_uint4(dq((q1 & 0x000F000Fu) | 0x64006400u, z2, s2),
                             dq(((q1 >> 4) & 0x000F000Fu) | 0x64006400u, z2, s2),
                             dq(((q1 >> 8) & 0x000F000Fu) | 0x64006400u, z2, s2),
                             dq(((q1 >> 12) & 0x000F000Fu) | 0x64006400u, z2, s2));
      *(uint4*)(Bs + sr * LDK + sg0 * 8) = bv0;
      *(uint4*)(Bs + sr * LDK + sg0 * 8 + 8) = bv1;
      __syncthreads();
      h8 af[4], bf[4];
#pragma unroll
      for (int i = 0; i < 4; ++i) {
        af[i] = *(const h8*)(Ab + i * 16 * LDK);
        bf[i] = *(const h8*)(Bb + i * 16 * LDK);
      }
#pragma unroll
      for (int i = 0; i < 4; ++i)
#pragma unroll
        for (int j = 0; j < 4; ++j)
          acc[i][j] = __builtin_amdgcn_mfma_f32_16x16x32_f16(af[i], bf[j],
                                                             acc[i][j], 0, 0, 0);
    }
  }
  const int r0 = bm0 + wm * 64 + (lane >> 4) * 4;
  const int c0 = bn0 + wn * 64 + (lane & 15);
#pragma unroll
  for (int j = 0; j < 4; ++j) {
    const int c = c0 + j * 16;
    const float bv = bias[c];
#pragma unroll
    for (int i = 0; i < 4; ++i)
#pragma unroll
      for (int rr = 0; rr < 4; ++rr)
        out[(size_t)(r0 + i * 16 + rr) * N + c] = acc[i][j][rr] + bv;
  }
}

extern "C" void kernel_launch(void* const* d_in, const int* in_sizes, int n_in,
                              void* d_out, int out_size, void* d_ws, size_t ws_size,
                              hipStream_t stream) {
  const float* x = (const float*)d_in[0];
  const uint32_t* qweight = (const uint32_t*)d_in[1];
  const uint32_t* qzeros = (const uint32_t*)d_in[2];
  const float* scales = (const float*)d_in[3];
  const float* bias = (const float*)d_in[4];
  float* out = (float*)d_out;

  const int out_f = in_sizes[4];            // 11008
  const int groups = in_sizes[3] / out_f;   // 32
  const int in_f = groups * 128;            // 4096
  const int tokens = in_sizes[0] / in_f;    // 4096

  const size_t need = ((size_t)tokens * in_f + (size_t)out_f * in_f) * 2;
  if (ws_size >= need) {
    _Float16* xh = (_Float16*)d_ws;
    _Float16* wt = xh + (size_t)tokens * in_f;

    size_t nx = (size_t)tokens * in_f;
    cvt_x_kernel<<<(nx + 2047) / 2048, 256, 0, stream>>>(x, xh, nx);

    dim3 gq(out_f / 64, (in_f / 8) / 8);    // 172 x 64
    dequant_w_kernel<<<gq, 256, 0, stream>>>(qweight, qzeros, scales, wt,
                                             out_f, in_f);

    if ((tokens % 256) == 0 && (out_f % 256) == 0 && (in_f % 32) == 0) {
      dim3 gg(out_f / 256, tokens / 256);   // 43 x 16
      gemm_f16_256<<<gg, 512, 0, stream>>>(xh, wt, bias, out,
                                           tokens, out_f, in_f);
    } else {
      dim3 gg(out_f / 128, tokens / 128);
      gemm_f16_kernel<<<gg, 256, 0, stream>>>(xh, wt, bias, out,
                                              tokens, out_f, in_f);
    }
  } else {
    dim3 grid(out_f / 128, tokens / 128);
    gptq_gemm_fused<<<grid, 256, 0, stream>>>(x, qweight, qzeros, scales, bias,
                                              out, tokens, out_f, in_f);
  }
}

// Round 2
// 655.994 us; speedup vs baseline: 1.2620x; 1.1720x over previous
//
#include <hip/hip_runtime.h>
#include <stdint.h>

typedef _Float16 h2 __attribute__((ext_vector_type(2)));
typedef _Float16 h8 __attribute__((ext_vector_type(8)));
typedef float f32x4 __attribute__((ext_vector_type(4)));

__device__ __forceinline__ uint32_t pk_cvt(float a, float b) {
  return __builtin_bit_cast(uint32_t, __builtin_amdgcn_cvt_pkrtz(a, b));
}

__device__ __forceinline__ uint32_t dq(uint32_t t, h2 z2, h2 s2) {
  // t = two f16 (1024+n_lo, 1024+n_hi); exact integer subtract, one rounded mul
  h2 v = __builtin_bit_cast(h2, t);
  h2 w = (v - z2) * s2;
  return __builtin_bit_cast(uint32_t, w);
}

__device__ __forceinline__ uint32_t dq_lin(uint32_t u, h2 z2, h2 s2) {
  // nibbles at bits 0-3 and 4-7 of u -> linear pair (k, k+1)
  uint32_t t = (u & 0xFu) | ((u & 0xF0u) << 12) | 0x64006400u;
  return dq(t, z2, s2);
}

typedef __attribute__((address_space(1))) const uint32_t* gas_ptr;
typedef __attribute__((address_space(3))) uint32_t* las_ptr;
__device__ __forceinline__ void gll16(const _Float16* g, _Float16* l) {
  // lane i lands at l + i*16B (wave-uniform base); 16B per lane
  __builtin_amdgcn_global_load_lds((gas_ptr)g, (las_ptr)l, 16, 0, 0);
}

#define WAITVM(n) asm volatile("s_waitcnt vmcnt(" #n ")" ::: "memory")
#define MEMFENCE  asm volatile("" ::: "memory")

// ---------------- phase 1: x fp32 -> f16 (linear k order) ----------------
__global__ __launch_bounds__(256) void cvt_x_kernel(const float* __restrict__ x,
                                                    _Float16* __restrict__ xh,
                                                    size_t n) {
  size_t i = ((size_t)blockIdx.x * 256 + threadIdx.x) * 8;
  if (i >= n) return;
  float4 a = *(const float4*)(x + i);
  float4 b = *(const float4*)(x + i + 4);
  uint4 v = make_uint4(pk_cvt(a.x, a.y), pk_cvt(a.z, a.w),
                       pk_cvt(b.x, b.y), pk_cvt(b.z, b.w));
  *(uint4*)(xh + i) = v;
}

// -------- phase 2: dequant qweight -> W^T f16 [N][K], linear k ----------
__global__ __launch_bounds__(256) void dequant_w_kernel(
    const uint32_t* __restrict__ qweight, const uint32_t* __restrict__ qzeros,
    const float* __restrict__ scales, _Float16* __restrict__ wt, int N, int K) {
  __shared__ uint32_t qw[8][64];
  const int t = threadIdx.x;
  const int n0 = blockIdx.x * 64;
  const int kp0 = blockIdx.y * 8;  // 8 packed words = 64 k, inside one group

  {  // coalesced load of the [8 kp][64 n] tile
    int r = t >> 6, c = t & 63;
    qw[r][c]     = qweight[(size_t)(kp0 + r) * N + n0 + c];
    qw[r + 4][c] = qweight[(size_t)(kp0 + r + 4) * N + n0 + c];
  }
  __syncthreads();

  const int nl = t >> 2;           // output row (column of W) 0..63
  const int kpl = (t & 3) * 2;     // this thread's 2 packed words
  const int n = n0 + nl;
  const int g = kp0 >> 4;          // group = k/128 = kp/16
  uint32_t qz = qzeros[(size_t)g * (N >> 3) + (n >> 3)];
  int zp = (qz >> ((n & 7) * 4)) & 15;
  float sc = scales[(size_t)g * N + n];
  _Float16 hz = (_Float16)(float)(1024 + zp + 1);
  _Float16 hs = (_Float16)sc;
  h2 z2 = {hz, hz};
  h2 s2 = {hs, hs};

#pragma unroll
  for (int w = 0; w < 2; ++w) {
    uint32_t word = qw[kpl + w][nl];
    uint4 v = make_uint4(dq_lin(word, z2, s2), dq_lin(word >> 8, z2, s2),
                         dq_lin(word >> 16, z2, s2), dq_lin(word >> 24, z2, s2));
    *(uint4*)(wt + (size_t)n * K + (size_t)(kp0 + kpl + w) * 8) = v;
  }
}

// ------------- phase 3a: 256x256 tile, m201-style 2-phase/K-tile --------
// A [M][K] f16, B [N][K] f16 (W^T). BK=32, 4-deep LDS ring (128 KiB),
// 8 waves (2M x 4N), per-wave output 128x64.
// Per K-tile: 2 phases, each {ds_read frags ; issue 2 gll (tile t+3) ;
// barrier ; lgkmcnt(0)+sched_barrier ; setprio(1) 16 MFMA setprio(0) ;
// barrier}. vmcnt confirm for tile t+1 at END of tile t (counted, vmcnt(8)
// steady state — never 0 in main loop). Barrier density = 1 per 8 k
// (matches m201). LDS swizzle slot ^= (row>>1)&3 (64B rows -> all 8 bank
// quads over 16 rows, 2-way = free), applied on BOTH sides: pre-swizzled
// per-lane GLOBAL source (gll writes linearly) + swizzled ds_read addr.
__global__ __launch_bounds__(512, 2) void gemm_f16_256(
    const _Float16* __restrict__ A, const _Float16* __restrict__ B,
    const float* __restrict__ bias, float* __restrict__ out,
    int M, int N, int K) {
  __shared__ _Float16 As[4][256 * 32];
  __shared__ _Float16 Bs[4][256 * 32];

  // bijective XCD-aware block swizzle (m204 form)
  const int gx = gridDim.x, gy = gridDim.y;
  const int nwg = gx * gy;
  const int lin = blockIdx.y * gx + blockIdx.x;
  const int xcd = lin & 7, idx = lin >> 3;
  const int q8 = nwg >> 3, r8 = nwg & 7;
  const int wg = (xcd < r8 ? xcd * (q8 + 1) : r8 * (q8 + 1) + (xcd - r8) * q8) + idx;
  const int bn0 = (wg % gx) * 256;
  const int bm0 = (wg / gx) * 256;

  const int tid = threadIdx.x;
  const int lane = tid & 63;
  const int wave = tid >> 6;     // 0..7
  const int wm = wave >> 2;      // 0..1 -> 128 rows
  const int wn = wave & 3;       // 0..3 -> 64 cols

  f32x4 acc[8][4];
#pragma unroll
  for (int i = 0; i < 8; ++i)
#pragma unroll
    for (int j = 0; j < 4; ++j) acc[i][j] = (f32x4)0.f;

  // ---- staging: wave w stages rows [32w,32w+32) of A and B ----
  // lane i -> lds row (chunk base)+(i>>2), slot i&3 (linear gll write).
  // source k-slot pre-swizzled: (i&3) ^ ((i>>3)&3)  [= slot ^ f(row),
  // f(row) = (row>>1)&3 with row = i>>2].
  const int srow = lane >> 2;                       // 0..15
  const int sslot = (lane & 3) ^ ((lane >> 3) & 3); // swizzled source slot
  const _Float16* pSa0 = A + (size_t)(bm0 + 32 * wave + srow) * K + sslot * 8;
  const _Float16* pSa1 = pSa0 + (size_t)16 * K;
  const _Float16* pSb0 = B + (size_t)(bn0 + 32 * wave + srow) * K + sslot * 8;
  const _Float16* pSb1 = pSb0 + (size_t)16 * K;
  const int dst_off = wave * 1024;                  // (32*wave)*32 halfs

  // ---- fragment read offsets: slot = (lane>>4) ^ f(row), row = lane&15 --
  const int fslot = ((lane >> 4) ^ ((lane >> 1) & 3)) * 8;
  const int aoff = (wm * 128 + (lane & 15)) * 32 + fslot;
  const int boff = (wn * 64 + (lane & 15)) * 32 + fslot;

  const int nt = K >> 5;  // K-tiles of 32

  // ---- prologue: stage tiles 0,1,2; confirm tile 0 landed ----
#pragma unroll
  for (int u = 0; u < 3; ++u) {
    if (u < nt) {
      const size_t ko = (size_t)u * 32;
      _Float16* da = As[u & 3] + dst_off;
      _Float16* db = Bs[u & 3] + dst_off;
      gll16(pSa0 + ko, da);
      gll16(pSa1 + ko, da + 512);
      gll16(pSb0 + ko, db);
      gll16(pSb1 + ko, db + 512);
    }
  }
  if (nt >= 3)      WAITVM(8);
  else if (nt == 2) WAITVM(4);
  else              WAITVM(0);
  __builtin_amdgcn_s_barrier();
  MEMFENCE;

  for (int t = 0; t < nt; ++t) {
    const int buf = t & 3;
    const _Float16* Ab = As[buf] + aoff;
    const _Float16* Bb = Bs[buf] + boff;
    const int ts = t + 3;
    const bool do_stage = ts < nt;
    const size_t ko = (size_t)ts * 32;
    _Float16* da = As[ts & 3] + dst_off;
    _Float16* db = Bs[ts & 3] + dst_off;

    h8 af[4], bf[4];
    // ================= phase 0: A rows 0..3 x all B =================
#pragma unroll
    for (int r = 0; r < 4; ++r) {
      af[r] = *(const h8*)(Ab + r * 512);
      bf[r] = *(const h8*)(Bb + r * 512);
    }
    if (do_stage) {
      gll16(pSa0 + ko, da);
      gll16(pSa1 + ko, da + 512);
    }
    __builtin_amdgcn_s_barrier();
    asm volatile("s_waitcnt lgkmcnt(0)" ::: "memory");
    __builtin_amdgcn_sched_barrier(0);
    __builtin_amdgcn_s_setprio(1);
#pragma unroll
    for (int r = 0; r < 4; ++r)
#pragma unroll
      for (int j = 0; j < 4; ++j)
        acc[r][j] = __builtin_amdgcn_mfma_f32_16x16x32_f16(af[r], bf[j],
                                                           acc[r][j], 0, 0, 0);
    __builtin_amdgcn_s_setprio(0);
    __builtin_amdgcn_s_barrier();
    MEMFENCE;

    // ================= phase 1: A rows 4..7 x all B =================
#pragma unroll
    for (int r = 0; r < 4; ++r) af[r] = *(const h8*)(Ab + (4 + r) * 512);
    if (do_stage) {
      gll16(pSb0 + ko, db);
      gll16(pSb1 + ko, db + 512);
    }
    // confirm tile t+1 landed before its phase-0 reads (next iteration).
    // steady state: t+1..t+3 in flight (12) -> wait to 8. never 0 mid-loop.
    if (do_stage)            WAITVM(8);
    else if (ts == nt)       WAITVM(4);
    else if (t + 2 == nt)    WAITVM(0);
    // t == nt-1: nothing outstanding to confirm
    __builtin_amdgcn_s_barrier();
    asm volatile("s_waitcnt lgkmcnt(0)" ::: "memory");
    __builtin_amdgcn_sched_barrier(0);
    __builtin_amdgcn_s_setprio(1);
#pragma unroll
    for (int r = 0; r < 4; ++r)
#pragma unroll
      for (int j = 0; j < 4; ++j)
        acc[4 + r][j] = __builtin_amdgcn_mfma_f32_16x16x32_f16(af[r], bf[j],
                                                               acc[4 + r][j],
                                                               0, 0, 0);
    __builtin_amdgcn_s_setprio(0);
    __builtin_amdgcn_s_barrier();
    MEMFENCE;
  }

  // epilogue: D[row=(lane>>4)*4+rr][col=lane&15] per 16x16 tile
  const int r0 = bm0 + wm * 128 + ((lane >> 4) << 2);
  const int c0 = bn0 + wn * 64 + (lane & 15);
#pragma unroll
  for (int j = 0; j < 4; ++j) {
    const int c = c0 + j * 16;
    const float bv = bias[c];
#pragma unroll
    for (int i = 0; i < 8; ++i) {
#pragma unroll
      for (int rr = 0; rr < 4; ++rr)
        out[(size_t)(r0 + i * 16 + rr) * N + c] = acc[i][j][rr] + bv;
    }
  }
}

// ------------- phase 3b fallback: f16 GEMM, m97 structure ---------------
__global__ __launch_bounds__(256) void gemm_f16_kernel(
    const _Float16* __restrict__ A,   // [M][K] f16
    const _Float16* __restrict__ B,   // [N][K] f16 (W^T)
    const float* __restrict__ bias, float* __restrict__ out,
    int M, int N, int K) {
  __shared__ _Float16 As[128 * 32];   // unpadded: required by global_load_lds
  __shared__ _Float16 Bs[128 * 32];

  const int tid = threadIdx.x;
  const int lane = tid & 63;
  const int wave = tid >> 6;
  const int wm = wave & 1;
  const int wn = wave >> 1;
  const int bn0 = blockIdx.x * 128;
  const int bm0 = blockIdx.y * 128;

  f32x4 acc[4][4];
#pragma unroll
  for (int i = 0; i < 4; ++i)
#pragma unroll
    for (int j = 0; j < 4; ++j) acc[i][j] = (f32x4)0.f;

  const int srow = wave * 16 + (lane >> 2);
  const int skoff = (lane & 3) * 8;
  const _Float16* Ag0 = A + (size_t)(bm0 + srow) * K + skoff;
  const _Float16* Ag1 = A + (size_t)(bm0 + 64 + srow) * K + skoff;
  const _Float16* Bg0 = B + (size_t)(bn0 + srow) * K + skoff;
  const _Float16* Bg1 = B + (size_t)(bn0 + 64 + srow) * K + skoff;
  _Float16* Al0 = As + (wave * 16) * 32;
  _Float16* Al1 = As + (64 + wave * 16) * 32;
  _Float16* Bl0 = Bs + (wave * 16) * 32;
  _Float16* Bl1 = Bs + (64 + wave * 16) * 32;

  const _Float16* Af = As + (wm * 64 + (lane & 15)) * 32 + (lane >> 4) * 8;
  const _Float16* Bf = Bs + (wn * 64 + (lane & 15)) * 32 + (lane >> 4) * 8;

  for (int k0 = 0; k0 < K; k0 += 32) {
    gll16(Ag0 + k0, Al0);
    gll16(Ag1 + k0, Al1);
    gll16(Bg0 + k0, Bl0);
    gll16(Bg1 + k0, Bl1);
    __syncthreads();

    h8 af[4], bf[4];
#pragma unroll
    for (int i = 0; i < 4; ++i) {
      af[i] = *(const h8*)(Af + i * 16 * 32);
      bf[i] = *(const h8*)(Bf + i * 16 * 32);
    }
#pragma unroll
    for (int i = 0; i < 4; ++i)
#pragma unroll
      for (int j = 0; j < 4; ++j)
        acc[i][j] = __builtin_amdgcn_mfma_f32_16x16x32_f16(af[i], bf[j],
                                                           acc[i][j], 0, 0, 0);
    __syncthreads();
  }

  const int r0 = bm0 + wm * 64 + (lane >> 4) * 4;
  const int c0 = bn0 + wn * 64 + (lane & 15);
#pragma unroll
  for (int j = 0; j < 4; ++j) {
    const int c = c0 + j * 16;
    const float bv = bias[c];
#pragma unroll
    for (int i = 0; i < 4; ++i) {
#pragma unroll
      for (int rr = 0; rr < 4; ++rr) {
        out[(size_t)(r0 + i * 16 + rr) * N + c] = acc[i][j][rr] + bv;
      }
    }
  }
}

// ------------------- fallback: round-2 fused kernel ---------------------
#define LDK 40
__global__ __launch_bounds__(256) void gptq_gemm_fused(
    const float* __restrict__ x, const uint32_t* __restrict__ qweight,
    const uint32_t* __restrict__ qzeros, const float* __restrict__ scales,
    const float* __restrict__ bias, float* __restrict__ out,
    int M, int N, int K) {
  __shared__ _Float16 As[128 * LDK];
  __shared__ _Float16 Bs[128 * LDK];
  const int tid = threadIdx.x, lane = tid & 63, wave = tid >> 6;
  const int wm = wave & 1, wn = wave >> 1;
  const int bn0 = blockIdx.x * 128, bm0 = blockIdx.y * 128;
  const int sr = tid >> 1, sg0 = (tid & 1) * 2;
  const float* xrow = x + (size_t)(bm0 + sr) * K + sg0 * 8;
  const int colb = bn0 + sr;
  const int groups = K >> 7, NP = N >> 3;
  f32x4 acc[4][4];
#pragma unroll
  for (int i = 0; i < 4; ++i)
#pragma unroll
    for (int j = 0; j < 4; ++j) acc[i][j] = (f32x4)0.f;
  const _Float16* Ab = As + (wm * 64 + (lane & 15)) * LDK + (lane >> 4) * 8;
  const _Float16* Bb = Bs + (wn * 64 + (lane & 15)) * LDK + (lane >> 4) * 8;
  for (int g = 0; g < groups; ++g) {
    uint32_t qz = qzeros[(size_t)g * NP + (colb >> 3)];
    int zp = (qz >> ((colb & 7) * 4)) & 15;
    float sc = scales[(size_t)g * N + colb];
    _Float16 hz = (_Float16)(float)(1024 + zp + 1);
    _Float16 hs = (_Float16)sc;
    h2 z2 = {hz, hz}, s2 = {hs, hs};
#pragma unroll
    for (int kt = 0; kt < 4; ++kt) {
      const int k0 = g * 128 + kt * 32;
      const float* xr = xrow + k0;
      float4 fa0 = *(const float4*)(xr);
      float4 fa1 = *(const float4*)(xr + 4);
      float4 fa2 = *(const float4*)(xr + 8);
      float4 fa3 = *(const float4*)(xr + 12);
      const size_t kp = (size_t)(k0 >> 3) + sg0;
      uint32_t q0 = qweight[kp * N + colb];
      uint32_t q1 = qweight[(kp + 1) * N + colb];
      __syncthreads();
      uint4 av0 = make_uint4(pk_cvt(fa0.x, fa1.x), pk_cvt(fa0.y, fa1.y),
                             pk_cvt(fa0.z, fa1.z), pk_cvt(fa0.w, fa1.w));
      uint4 av1 = make_uint4(pk_cvt(fa2.x, fa3.x), pk_cvt(fa2.y, fa3.y),
                             pk_cvt(fa2.z, fa3.z), pk_cvt(fa2.w, fa3.w));
      *(uint4*)(As + sr * LDK + sg0 * 8) = av0;
      *(uint4*)(As + sr * LDK + sg0 * 8 + 8) = av1;
      uint4 bv0 = make_uint4(dq((q0 & 0x000F000Fu) | 0x64006400u, z2, s2),
                             dq(((q0 >> 4) & 0x000F000Fu) | 0x64006400u, z2, s2),
                             dq(((q0 >> 8) & 0x000F000Fu) | 0x64006400u, z2, s2),
                             dq(((q0 >> 12) & 0x000F000Fu) | 0x64006400u, z2, s2));
      uint4 bv1 = make_uint4(dq((q1 & 0x000F000Fu) | 0x64006400u, z2, s2),
                             dq(((q1 >> 4) & 0x000F000Fu) | 0x64006400u, z2, s2),
                             dq(((q1 >> 8) & 0x000F000Fu) | 0x64006400u, z2, s2),
                             dq(((q1 >> 12) & 0x000F000Fu) | 0x64006400u, z2, s2));
      *(uint4*)(Bs + sr * LDK + sg0 * 8) = bv0;
      *(uint4*)(Bs + sr * LDK + sg0 * 8 + 8) = bv1;
      __syncthreads();
      h8 af[4], bf[4];
#pragma unroll
      for (int i = 0; i < 4; ++i) {
        af[i] = *(const h8*)(Ab + i * 16 * LDK);
        bf[i] = *(const h8*)(Bb + i * 16 * LDK);
      }
#pragma unroll
      for (int i = 0; i < 4; ++i)
#pragma unroll
        for (int j = 0; j < 4; ++j)
          acc[i][j] = __builtin_amdgcn_mfma_f32_16x16x32_f16(af[i], bf[j],
                                                             acc[i][j], 0, 0, 0);
    }
  }
  const int r0 = bm0 + wm * 64 + (lane >> 4) * 4;
  const int c0 = bn0 + wn * 64 + (lane & 15);
#pragma unroll
  for (int j = 0; j < 4; ++j) {
    const int c = c0 + j * 16;
    const float bv = bias[c];
#pragma unroll
    for (int i = 0; i < 4; ++i)
#pragma unroll
      for (int rr = 0; rr < 4; ++rr)
        out[(size_t)(r0 + i * 16 + rr) * N + c] = acc[i][j][rr] + bv;
  }
}

extern "C" void kernel_launch(void* const* d_in, const int* in_sizes, int n_in,
                              void* d_out, int out_size, void* d_ws, size_t ws_size,
                              hipStream_t stream) {
  const float* x = (const float*)d_in[0];
  const uint32_t* qweight = (const uint32_t*)d_in[1];
  const uint32_t* qzeros = (const uint32_t*)d_in[2];
  const float* scales = (const float*)d_in[3];
  const float* bias = (const float*)d_in[4];
  float* out = (float*)d_out;

  const int out_f = in_sizes[4];            // 11008
  const int groups = in_sizes[3] / out_f;   // 32
  const int in_f = groups * 128;            // 4096
  const int tokens = in_sizes[0] / in_f;    // 4096

  const size_t need = ((size_t)tokens * in_f + (size_t)out_f * in_f) * 2;
  if (ws_size >= need) {
    _Float16* xh = (_Float16*)d_ws;
    _Float16* wt = xh + (size_t)tokens * in_f;

    size_t nx = (size_t)tokens * in_f;
    cvt_x_kernel<<<(nx + 2047) / 2048, 256, 0, stream>>>(x, xh, nx);

    dim3 gq(out_f / 64, (in_f / 8) / 8);    // 172 x 64
    dequant_w_kernel<<<gq, 256, 0, stream>>>(qweight, qzeros, scales, wt,
                                             out_f, in_f);

    if ((tokens % 256) == 0 && (out_f % 256) == 0 && (in_f % 32) == 0) {
      dim3 gg(out_f / 256, tokens / 256);   // 43 x 16
      gemm_f16_256<<<gg, 512, 0, stream>>>(xh, wt, bias, out,
                                           tokens, out_f, in_f);
    } else {
      dim3 gg(out_f / 128, tokens / 128);
      gemm_f16_kernel<<<gg, 256, 0, stream>>>(xh, wt, bias, out,
                                              tokens, out_f, in_f);
    }
  } else {
    dim3 grid(out_f / 128, tokens / 128);
    gptq_gemm_fused<<<grid, 256, 0, stream>>>(x, qweight, qzeros, scales, bias,
                                              out, tokens, out_f, in_f);
  }
}

// Round 3
// 607.320 us; speedup vs baseline: 1.3632x; 1.0801x over previous
//
#include <hip/hip_runtime.h>
#include <stdint.h>

typedef _Float16 h2 __attribute__((ext_vector_type(2)));
typedef _Float16 h8 __attribute__((ext_vector_type(8)));
typedef float f32x4 __attribute__((ext_vector_type(4)));

__device__ __forceinline__ uint32_t pk_cvt(float a, float b) {
  return __builtin_bit_cast(uint32_t, __builtin_amdgcn_cvt_pkrtz(a, b));
}

__device__ __forceinline__ uint32_t dq(uint32_t t, h2 z2, h2 s2) {
  // t = two f16 (1024+n_lo, 1024+n_hi); exact integer subtract, one rounded mul
  h2 v = __builtin_bit_cast(h2, t);
  h2 w = (v - z2) * s2;
  return __builtin_bit_cast(uint32_t, w);
}

__device__ __forceinline__ uint32_t dq_lin(uint32_t u, h2 z2, h2 s2) {
  // nibbles at bits 0-3 and 4-7 of u -> linear pair (k, k+1)
  uint32_t t = (u & 0xFu) | ((u & 0xF0u) << 12) | 0x64006400u;
  return dq(t, z2, s2);
}

typedef __attribute__((address_space(1))) const uint32_t* gas_ptr;
typedef __attribute__((address_space(3))) uint32_t* las_ptr;
__device__ __forceinline__ void gll16(const _Float16* g, _Float16* l) {
  // lane i lands at l + i*16B (wave-uniform base); 16B per lane
  __builtin_amdgcn_global_load_lds((gas_ptr)g, (las_ptr)l, 16, 0, 0);
}

#define WAITVM(n) asm volatile("s_waitcnt vmcnt(" #n ")" ::: "memory")
#define WAITLGKM(n) asm volatile("s_waitcnt lgkmcnt(" #n ")" ::: "memory")
#define MEMFENCE  asm volatile("" ::: "memory")

// ---- fused prep: x fp32->f16 cvt + qweight dequant -> W^T f16 [N][K] ----
// Two independent workloads in one launch so they overlap on the device.
__global__ __launch_bounds__(256) void prep_kernel(
    const float* __restrict__ x, _Float16* __restrict__ xh, size_t nx,
    int nxb,
    const uint32_t* __restrict__ qweight, const uint32_t* __restrict__ qzeros,
    const float* __restrict__ scales, _Float16* __restrict__ wt, int N, int K) {
  __shared__ uint32_t qw[8][64];
  const int bid = blockIdx.x;
  if (bid < nxb) {
    // ---------------- cvt region ----------------
    size_t i = ((size_t)bid * 256 + threadIdx.x) * 8;
    if (i >= nx) return;
    float4 a = *(const float4*)(x + i);
    float4 b = *(const float4*)(x + i + 4);
    uint4 v = make_uint4(pk_cvt(a.x, a.y), pk_cvt(a.z, a.w),
                         pk_cvt(b.x, b.y), pk_cvt(b.z, b.w));
    *(uint4*)(xh + i) = v;
    return;
  }
  // ---------------- dequant region ----------------
  const int dqb = bid - nxb;
  const int nblk = N >> 6;
  const int t = threadIdx.x;
  const int n0 = (dqb % nblk) * 64;
  const int kp0 = (dqb / nblk) * 8;  // 8 packed words = 64 k, inside one group

  {  // coalesced load of the [8 kp][64 n] tile
    int r = t >> 6, c = t & 63;
    qw[r][c]     = qweight[(size_t)(kp0 + r) * N + n0 + c];
    qw[r + 4][c] = qweight[(size_t)(kp0 + r + 4) * N + n0 + c];
  }
  __syncthreads();

  const int nl = t >> 2;           // output row (column of W) 0..63
  const int kpl = (t & 3) * 2;     // this thread's 2 packed words
  const int n = n0 + nl;
  const int g = kp0 >> 4;          // group = k/128 = kp/16
  uint32_t qz = qzeros[(size_t)g * (N >> 3) + (n >> 3)];
  int zp = (qz >> ((n & 7) * 4)) & 15;
  float sc = scales[(size_t)g * N + n];
  _Float16 hz = (_Float16)(float)(1024 + zp + 1);
  _Float16 hs = (_Float16)sc;
  h2 z2 = {hz, hz};
  h2 s2 = {hs, hs};

#pragma unroll
  for (int w = 0; w < 2; ++w) {
    uint32_t word = qw[kpl + w][nl];
    uint4 v = make_uint4(dq_lin(word, z2, s2), dq_lin(word >> 8, z2, s2),
                         dq_lin(word >> 16, z2, s2), dq_lin(word >> 24, z2, s2));
    *(uint4*)(wt + (size_t)n * K + (size_t)(kp0 + kpl + w) * 8) = v;
  }
}

// ------------- phase 3a: 256x256 tile, 1-barrier/K-tile pipeline --------
// A [M][K] f16, B [N][K] f16 (W^T). BK=32, 4-deep LDS ring (128 KiB),
// 8 waves (2M x 4N), per-wave output 128x64.
// Per K-tile: WAITVM(8) (counted; tiles t+1,t+2 stay in flight, never 0
// mid-loop) + ONE s_barrier. Ring depth 4 makes MFMA-side barriers
// unnecessary: glls issued in tile t overwrite buffer (t-1)&3, whose reads
// completed (lgkmcnt-drained) before every wave reached the tile-t barrier.
// All 12 ds_reads issued up front; lgkmcnt(4) gates MFMA cluster 0 (first
// 8 reads), lgkmcnt(0) gates cluster 1 -> LDS latency hides under MFMA,
// and waves drift within a tile so ds_read(w1) overlaps MFMA(w0) per SIMD.
// LDS swizzle slot ^= (row>>1)&3 on BOTH sides (conflicts measured 0).
__global__ __launch_bounds__(512, 2) void gemm_f16_256(
    const _Float16* __restrict__ A, const _Float16* __restrict__ B,
    const float* __restrict__ bias, float* __restrict__ out,
    int M, int N, int K) {
  __shared__ _Float16 As[4][256 * 32];
  __shared__ _Float16 Bs[4][256 * 32];

  // bijective XCD-aware block swizzle (m204 form)
  const int gx = gridDim.x, gy = gridDim.y;
  const int nwg = gx * gy;
  const int lin = blockIdx.y * gx + blockIdx.x;
  const int xcd = lin & 7, idx = lin >> 3;
  const int q8 = nwg >> 3, r8 = nwg & 7;
  const int wg = (xcd < r8 ? xcd * (q8 + 1) : r8 * (q8 + 1) + (xcd - r8) * q8) + idx;
  const int bn0 = (wg % gx) * 256;
  const int bm0 = (wg / gx) * 256;

  const int tid = threadIdx.x;
  const int lane = tid & 63;
  const int wave = tid >> 6;     // 0..7
  const int wm = wave >> 2;      // 0..1 -> 128 rows
  const int wn = wave & 3;       // 0..3 -> 64 cols

  f32x4 acc[8][4];
#pragma unroll
  for (int i = 0; i < 8; ++i)
#pragma unroll
    for (int j = 0; j < 4; ++j) acc[i][j] = (f32x4)0.f;

  // ---- staging: wave w stages rows [32w,32w+32) of A and B ----
  // lane i -> lds row (chunk base)+(i>>2), slot i&3 (linear gll write).
  // source k-slot pre-swizzled: (i&3) ^ ((i>>3)&3).
  const int srow = lane >> 2;                       // 0..15
  const int sslot = (lane & 3) ^ ((lane >> 3) & 3); // swizzled source slot
  const _Float16* pSa0 = A + (size_t)(bm0 + 32 * wave + srow) * K + sslot * 8;
  const _Float16* pSa1 = pSa0 + (size_t)16 * K;
  const _Float16* pSb0 = B + (size_t)(bn0 + 32 * wave + srow) * K + sslot * 8;
  const _Float16* pSb1 = pSb0 + (size_t)16 * K;
  const int dst_off = wave * 1024;                  // (32*wave)*32 halfs

  // ---- fragment read offsets: slot = (lane>>4) ^ f(row), row = lane&15 --
  const int fslot = ((lane >> 4) ^ ((lane >> 1) & 3)) * 8;
  const int aoff = (wm * 128 + (lane & 15)) * 32 + fslot;
  const int boff = (wn * 64 + (lane & 15)) * 32 + fslot;

  const int nt = K >> 5;  // K-tiles of 32

  // ---- prologue: stage tiles 0,1,2 ----
#pragma unroll
  for (int u = 0; u < 3; ++u) {
    if (u < nt) {
      const size_t ko = (size_t)u * 32;
      _Float16* da = As[u & 3] + dst_off;
      _Float16* db = Bs[u & 3] + dst_off;
      gll16(pSa0 + ko, da);
      gll16(pSa1 + ko, da + 512);
      gll16(pSb0 + ko, db);
      gll16(pSb1 + ko, db + 512);
    }
  }

  for (int t = 0; t < nt; ++t) {
    // confirm own glls for tile t landed; after the barrier, everyone's
    // tile-t data is visible AND all tile-(t-1) reads are complete.
    if (t < nt - 2)       WAITVM(8);
    else if (t == nt - 2) WAITVM(4);
    else                  WAITVM(0);
    __builtin_amdgcn_s_barrier();
    MEMFENCE;

    const int buf = t & 3;
    const _Float16* Ab = As[buf] + aoff;
    const _Float16* Bb = Bs[buf] + boff;

    h8 bf[4], af0[4], af1[4];
#pragma unroll
    for (int r = 0; r < 4; ++r) bf[r] = *(const h8*)(Bb + r * 512);
#pragma unroll
    for (int r = 0; r < 4; ++r) af0[r] = *(const h8*)(Ab + r * 512);
#pragma unroll
    for (int r = 0; r < 4; ++r) af1[r] = *(const h8*)(Ab + (4 + r) * 512);

    const int ts = t + 3;
    if (ts < nt) {  // stage tile t+3 into buffer (t-1)&3 (reads done)
      const size_t ko = (size_t)ts * 32;
      _Float16* da = As[ts & 3] + dst_off;
      _Float16* db = Bs[ts & 3] + dst_off;
      gll16(pSa0 + ko, da);
      gll16(pSa1 + ko, da + 512);
      gll16(pSb0 + ko, db);
      gll16(pSb1 + ko, db + 512);
    }

    WAITLGKM(4);   // first 8 reads (bf, af0) complete
    __builtin_amdgcn_sched_barrier(0);
    __builtin_amdgcn_s_setprio(1);
#pragma unroll
    for (int r = 0; r < 4; ++r)
#pragma unroll
      for (int j = 0; j < 4; ++j)
        acc[r][j] = __builtin_amdgcn_mfma_f32_16x16x32_f16(af0[r], bf[j],
                                                           acc[r][j], 0, 0, 0);
    __builtin_amdgcn_s_setprio(0);

    WAITLGKM(0);   // af1 complete
    __builtin_amdgcn_sched_barrier(0);
    __builtin_amdgcn_s_setprio(1);
#pragma unroll
    for (int r = 0; r < 4; ++r)
#pragma unroll
      for (int j = 0; j < 4; ++j)
        acc[4 + r][j] = __builtin_amdgcn_mfma_f32_16x16x32_f16(af1[r], bf[j],
                                                               acc[4 + r][j],
                                                               0, 0, 0);
    __builtin_amdgcn_s_setprio(0);
  }

  // epilogue: D[row=(lane>>4)*4+rr][col=lane&15] per 16x16 tile
  const int r0 = bm0 + wm * 128 + ((lane >> 4) << 2);
  const int c0 = bn0 + wn * 64 + (lane & 15);
#pragma unroll
  for (int j = 0; j < 4; ++j) {
    const int c = c0 + j * 16;
    const float bv = bias[c];
#pragma unroll
    for (int i = 0; i < 8; ++i) {
#pragma unroll
      for (int rr = 0; rr < 4; ++rr)
        out[(size_t)(r0 + i * 16 + rr) * N + c] = acc[i][j][rr] + bv;
    }
  }
}

// ------------- phase 3b fallback: f16 GEMM, m97 structure ---------------
__global__ __launch_bounds__(256) void gemm_f16_kernel(
    const _Float16* __restrict__ A,   // [M][K] f16
    const _Float16* __restrict__ B,   // [N][K] f16 (W^T)
    const float* __restrict__ bias, float* __restrict__ out,
    int M, int N, int K) {
  __shared__ _Float16 As[128 * 32];   // unpadded: required by global_load_lds
  __shared__ _Float16 Bs[128 * 32];

  const int tid = threadIdx.x;
  const int lane = tid & 63;
  const int wave = tid >> 6;
  const int wm = wave & 1;
  const int wn = wave >> 1;
  const int bn0 = blockIdx.x * 128;
  const int bm0 = blockIdx.y * 128;

  f32x4 acc[4][4];
#pragma unroll
  for (int i = 0; i < 4; ++i)
#pragma unroll
    for (int j = 0; j < 4; ++j) acc[i][j] = (f32x4)0.f;

  const int srow = wave * 16 + (lane >> 2);
  const int skoff = (lane & 3) * 8;
  const _Float16* Ag0 = A + (size_t)(bm0 + srow) * K + skoff;
  const _Float16* Ag1 = A + (size_t)(bm0 + 64 + srow) * K + skoff;
  const _Float16* Bg0 = B + (size_t)(bn0 + srow) * K + skoff;
  const _Float16* Bg1 = B + (size_t)(bn0 + 64 + srow) * K + skoff;
  _Float16* Al0 = As + (wave * 16) * 32;
  _Float16* Al1 = As + (64 + wave * 16) * 32;
  _Float16* Bl0 = Bs + (wave * 16) * 32;
  _Float16* Bl1 = Bs + (64 + wave * 16) * 32;

  const _Float16* Af = As + (wm * 64 + (lane & 15)) * 32 + (lane >> 4) * 8;
  const _Float16* Bf = Bs + (wn * 64 + (lane & 15)) * 32 + (lane >> 4) * 8;

  for (int k0 = 0; k0 < K; k0 += 32) {
    gll16(Ag0 + k0, Al0);
    gll16(Ag1 + k0, Al1);
    gll16(Bg0 + k0, Bl0);
    gll16(Bg1 + k0, Bl1);
    __syncthreads();

    h8 af[4], bf[4];
#pragma unroll
    for (int i = 0; i < 4; ++i) {
      af[i] = *(const h8*)(Af + i * 16 * 32);
      bf[i] = *(const h8*)(Bf + i * 16 * 32);
    }
#pragma unroll
    for (int i = 0; i < 4; ++i)
#pragma unroll
      for (int j = 0; j < 4; ++j)
        acc[i][j] = __builtin_amdgcn_mfma_f32_16x16x32_f16(af[i], bf[j],
                                                           acc[i][j], 0, 0, 0);
    __syncthreads();
  }

  const int r0 = bm0 + wm * 64 + (lane >> 4) * 4;
  const int c0 = bn0 + wn * 64 + (lane & 15);
#pragma unroll
  for (int j = 0; j < 4; ++j) {
    const int c = c0 + j * 16;
    const float bv = bias[c];
#pragma unroll
    for (int i = 0; i < 4; ++i) {
#pragma unroll
      for (int rr = 0; rr < 4; ++rr) {
        out[(size_t)(r0 + i * 16 + rr) * N + c] = acc[i][j][rr] + bv;
      }
    }
  }
}

// ------------------- fallback: round-2 fused kernel ---------------------
#define LDK 40
__global__ __launch_bounds__(256) void gptq_gemm_fused(
    const float* __restrict__ x, const uint32_t* __restrict__ qweight,
    const uint32_t* __restrict__ qzeros, const float* __restrict__ scales,
    const float* __restrict__ bias, float* __restrict__ out,
    int M, int N, int K) {
  __shared__ _Float16 As[128 * LDK];
  __shared__ _Float16 Bs[128 * LDK];
  const int tid = threadIdx.x, lane = tid & 63, wave = tid >> 6;
  const int wm = wave & 1, wn = wave >> 1;
  const int bn0 = blockIdx.x * 128, bm0 = blockIdx.y * 128;
  const int sr = tid >> 1, sg0 = (tid & 1) * 2;
  const float* xrow = x + (size_t)(bm0 + sr) * K + sg0 * 8;
  const int colb = bn0 + sr;
  const int groups = K >> 7, NP = N >> 3;
  f32x4 acc[4][4];
#pragma unroll
  for (int i = 0; i < 4; ++i)
#pragma unroll
    for (int j = 0; j < 4; ++j) acc[i][j] = (f32x4)0.f;
  const _Float16* Ab = As + (wm * 64 + (lane & 15)) * LDK + (lane >> 4) * 8;
  const _Float16* Bb = Bs + (wn * 64 + (lane & 15)) * LDK + (lane >> 4) * 8;
  for (int g = 0; g < groups; ++g) {
    uint32_t qz = qzeros[(size_t)g * NP + (colb >> 3)];
    int zp = (qz >> ((colb & 7) * 4)) & 15;
    float sc = scales[(size_t)g * N + colb];
    _Float16 hz = (_Float16)(float)(1024 + zp + 1);
    _Float16 hs = (_Float16)sc;
    h2 z2 = {hz, hz}, s2 = {hs, hs};
#pragma unroll
    for (int kt = 0; kt < 4; ++kt) {
      const int k0 = g * 128 + kt * 32;
      const float* xr = xrow + k0;
      float4 fa0 = *(const float4*)(xr);
      float4 fa1 = *(const float4*)(xr + 4);
      float4 fa2 = *(const float4*)(xr + 8);
      float4 fa3 = *(const float4*)(xr + 12);
      const size_t kp = (size_t)(k0 >> 3) + sg0;
      uint32_t q0 = qweight[kp * N + colb];
      uint32_t q1 = qweight[(kp + 1) * N + colb];
      __syncthreads();
      uint4 av0 = make_uint4(pk_cvt(fa0.x, fa1.x), pk_cvt(fa0.y, fa1.y),
                             pk_cvt(fa0.z, fa1.z), pk_cvt(fa0.w, fa1.w));
      uint4 av1 = make_uint4(pk_cvt(fa2.x, fa3.x), pk_cvt(fa2.y, fa3.y),
                             pk_cvt(fa2.z, fa3.z), pk_cvt(fa2.w, fa3.w));
      *(uint4*)(As + sr * LDK + sg0 * 8) = av0;
      *(uint4*)(As + sr * LDK + sg0 * 8 + 8) = av1;
      uint4 bv0 = make_uint4(dq((q0 & 0x000F000Fu) | 0x64006400u, z2, s2),
                             dq(((q0 >> 4) & 0x000F000Fu) | 0x64006400u, z2, s2),
                             dq(((q0 >> 8) & 0x000F000Fu) | 0x64006400u, z2, s2),
                             dq(((q0 >> 12) & 0x000F000Fu) | 0x64006400u, z2, s2));
      uint4 bv1 = make_uint4(dq((q1 & 0x000F000Fu) | 0x64006400u, z2, s2),
                             dq(((q1 >> 4) & 0x000F000Fu) | 0x64006400u, z2, s2),
                             dq(((q1 >> 8) & 0x000F000Fu) | 0x64006400u, z2, s2),
                             dq(((q1 >> 12) & 0x000F000Fu) | 0x64006400u, z2, s2));
      *(uint4*)(Bs + sr * LDK + sg0 * 8) = bv0;
      *(uint4*)(Bs + sr * LDK + sg0 * 8 + 8) = bv1;
      __syncthreads();
      h8 af[4], bf[4];
#pragma unroll
      for (int i = 0; i < 4; ++i) {
        af[i] = *(const h8*)(Ab + i * 16 * LDK);
        bf[i] = *(const h8*)(Bb + i * 16 * LDK);
      }
#pragma unroll
      for (int i = 0; i < 4; ++i)
#pragma unroll
        for (int j = 0; j < 4; ++j)
          acc[i][j] = __builtin_amdgcn_mfma_f32_16x16x32_f16(af[i], bf[j],
                                                             acc[i][j], 0, 0, 0);
    }
  }
  const int r0 = bm0 + wm * 64 + (lane >> 4) * 4;
  const int c0 = bn0 + wn * 64 + (lane & 15);
#pragma unroll
  for (int j = 0; j < 4; ++j) {
    const int c = c0 + j * 16;
    const float bv = bias[c];
#pragma unroll
    for (int i = 0; i < 4; ++i)
#pragma unroll
      for (int rr = 0; rr < 4; ++rr)
        out[(size_t)(r0 + i * 16 + rr) * N + c] = acc[i][j][rr] + bv;
  }
}

extern "C" void kernel_launch(void* const* d_in, const int* in_sizes, int n_in,
                              void* d_out, int out_size, void* d_ws, size_t ws_size,
                              hipStream_t stream) {
  const float* x = (const float*)d_in[0];
  const uint32_t* qweight = (const uint32_t*)d_in[1];
  const uint32_t* qzeros = (const uint32_t*)d_in[2];
  const float* scales = (const float*)d_in[3];
  const float* bias = (const float*)d_in[4];
  float* out = (float*)d_out;

  const int out_f = in_sizes[4];            // 11008
  const int groups = in_sizes[3] / out_f;   // 32
  const int in_f = groups * 128;            // 4096
  const int tokens = in_sizes[0] / in_f;    // 4096

  const size_t need = ((size_t)tokens * in_f + (size_t)out_f * in_f) * 2;
  if (ws_size >= need) {
    _Float16* xh = (_Float16*)d_ws;
    _Float16* wt = xh + (size_t)tokens * in_f;

    size_t nx = (size_t)tokens * in_f;
    const int nxb = (int)((nx + 2047) / 2048);
    const int ndq = (out_f / 64) * (in_f / 64);
    prep_kernel<<<nxb + ndq, 256, 0, stream>>>(x, xh, nx, nxb, qweight, qzeros,
                                               scales, wt, out_f, in_f);

    if ((tokens % 256) == 0 && (out_f % 256) == 0 && (in_f % 32) == 0) {
      dim3 gg(out_f / 256, tokens / 256);   // 43 x 16
      gemm_f16_256<<<gg, 512, 0, stream>>>(xh, wt, bias, out,
                                           tokens, out_f, in_f);
    } else {
      dim3 gg(out_f / 128, tokens / 128);
      gemm_f16_kernel<<<gg, 256, 0, stream>>>(xh, wt, bias, out,
                                              tokens, out_f, in_f);
    }
  } else {
    dim3 grid(out_f / 128, tokens / 128);
    gptq_gemm_fused<<<grid, 256, 0, stream>>>(x, qweight, qzeros, scales, bias,
                                              out, tokens, out_f, in_f);
  }
}